// Round 10
// baseline (88.365 us; speedup 1.0000x reference)
//
#include <hip/hip_runtime.h>
#include <math.h>

#define PBDIM 256   // prep kernel block
#define BDIM  64    // fused kernel: ONE wave per block

constexpr int Vc = 20000, Cc = 32, NBc = 12, KSc = 9, OUTc = 32;
constexpr int NTASK = 40000;
constexpr int MT    = 16;              // tasks per wave (MFMA M)
constexpr int NITER = NTASK / MT;      // 2500 exact = grid size
constexpr int UXH   = 16;              // halves per ux row (32 B, one cache line)
constexpr int XHS   = 32;              // halves per x_h row (64 B, one cache line)
constexpr int WFE   = KSc * 2 * 64 * 8;  // 9216 frag elems (hi); lo follows

typedef _Float16 half8 __attribute__((ext_vector_type(8)));  // 8 f16 = 4 VGPRs
typedef __attribute__((ext_vector_type(4))) float floatx4;   // MFMA C/D

// ---------- kernel 1: ux_h + x_h build (blocks 0..156) + W f16 frag build (157..192) ----------
__global__ __launch_bounds__(PBDIM)
void prep_kernel(const float* __restrict__ x, const float* __restrict__ u,
                 const float* __restrict__ W, _Float16* __restrict__ uxh,
                 _Float16* __restrict__ xh, _Float16* __restrict__ wf)
{
    if (blockIdx.x < 157) {
        __shared__ float us[Cc * KSc];
        for (int i = threadIdx.x; i < Cc * KSc; i += PBDIM) us[i] = u[i];
        __syncthreads();
        const int row = blockIdx.x * PBDIM + threadIdx.x;
        if (row >= NTASK) return;
        const float4* xr = (const float4*)(x + row * Cc);
        float4 xv[8];
#pragma unroll
        for (int i = 0; i < 8; ++i) xv[i] = xr[i];
        float acc[KSc];
#pragma unroll
        for (int k = 0; k < KSc; ++k) acc[k] = 0.f;
#pragma unroll
        for (int c = 0; c < Cc; ++c) {
            const float xc = ((const float*)xv)[c];
#pragma unroll
            for (int k = 0; k < KSc; ++k) acc[k] = fmaf(xc, us[c * KSc + k], acc[k]);
        }
        // ux row -> fp16, 32-B aligned (halves 0..8 used)
        half8 o;
#pragma unroll
        for (int k = 0; k < 8; ++k) o[k] = (_Float16)acc[k];
        *(half8*)(uxh + row * UXH) = o;
        uxh[row * UXH + 8] = (_Float16)acc[8];
        // x row -> fp16, 64-B aligned
#pragma unroll
        for (int q = 0; q < 4; ++q) {
            half8 hx;
#pragma unroll
            for (int j = 0; j < 8; ++j) hx[j] = (_Float16)((const float*)xv)[q * 8 + j];
            *(half8*)(xh + row * XHS + q * 8) = hx;
        }
    } else {
        // W f16 hi/lo MFMA B-fragments, B[c][o] layout for 16x16x32
        const int e = (blockIdx.x - 157) * PBDIM + threadIdx.x;   // [0, 9216)
        if (e >= WFE) return;
        const int j = e & 7;
        const int l = (e >> 3) & 63;
        const int h = (e >> 9) & 1;
        const int k = e >> 10;                  // 0..8
        const int c = (l >> 4) * 8 + j;         // B k-dim elem = channel
        const int o = (l & 15) + 16 * h;        // B n-dim = output col
        const float w = W[(c * KSc + k) * OUTc + o];
        const _Float16 wh = (_Float16)w;
        const _Float16 wl = (_Float16)(w - (float)wh);
        wf[e]       = wh;
        wf[WFE + e] = wl;
    }
}

// ---------- kernel 2: one wave = 16 tasks; register-dieted, no barriers ----------
__global__ __launch_bounds__(BDIM, 3)
void fused_kernel(const float* __restrict__ cvec, const float* __restrict__ bvec,
                  const int* __restrict__ adj, const _Float16* __restrict__ uxh,
                  const _Float16* __restrict__ xh, const _Float16* __restrict__ wf,
                  float* __restrict__ out)
{
    __shared__ __align__(16) float qs[MT][KSc][NBc];   // 6912 B, only LDS use

    const int l64 = threadIdx.x;
    const int oo  = l64 & 15;     // MFMA n / D col
    const int cb  = l64 >> 4;     // c-block for A, row-quad for D
    const int t0  = blockIdx.x * MT;

    float ck[KSc];
#pragma unroll
    for (int k = 0; k < KSc; ++k) ck[k] = cvec[k];

    // ---- per-lane task metadata; gather x rows; convert to fp32 immediately so
    //      rows[]/half-regs die before softmax (peak live ~150 < 170 cap) ----
    const int tA   = l64 & 15;                     // this lane's task (A row)
    const int task = t0 + tA;
    const int bb   = (task >= Vc) ? 1 : 0;
    const int v    = task - bb * Vc;
    float inv_local;
    float xs[NBc][8];                              // 96 VGPR: the big resident array
    {
        const int4* ar = (const int4*)(adj + v * NBc);   // 768 B/wave, L1-broadcast
        const int4 a0 = ar[0], a1 = ar[1], a2 = ar[2];
        int jv[NBc];
        jv[0] = a0.x; jv[1] = a0.y; jv[2]  = a0.z; jv[3]  = a0.w;
        jv[4] = a1.x; jv[5] = a1.y; jv[6]  = a1.z; jv[7]  = a1.w;
        jv[8] = a2.x; jv[9] = a2.y; jv[10] = a2.z; jv[11] = a2.w;
        int d = 0;
        int rows[NBc];
#pragma unroll
        for (int n = 0; n < NBc; ++n) {
            const bool pr = (jv[n] != 0);
            d += pr ? 1 : 0;
            rows[n] = pr ? (bb * Vc + jv[n] - 1) : 0;
        }
        inv_local = (d > 0) ? 1.f / (float)d : 0.f;
        half8 xr[NBc];                              // transient: dead after convert
#pragma unroll
        for (int n = 0; n < NBc; ++n)
            xr[n] = *(const half8*)(xh + rows[n] * XHS + cb * 8);
#pragma unroll
        for (int n = 0; n < NBc; ++n)
#pragma unroll
            for (int j = 0; j < 8; ++j) xs[n][j] = (float)xr[n][j];
    }

    // ---- softmax: 3 passes x 64 lanes = 16 tasks x 12 neighbors ----
#pragma unroll
    for (int p = 0; p < 3; ++p) {
        const int unit = p * 64 + l64;              // [0,192)
        const int t    = (unit * 171) >> 11;        // floor(unit/12), exact for unit<192
        const int n    = unit - t * 12;
        const int tk   = t0 + t;
        const int bbp  = (tk >= Vc) ? 1 : 0;
        const int vp   = tk - bbp * Vc;
        const int jn   = adj[vp * NBc + n];         // coalesced (contiguous units)
        const bool pred = (jn != 0);
        const int row = pred ? (bbp * Vc + jn - 1) : 0;
        const half8 uo8 = *(const half8*)(uxh + tk * UXH);
        const _Float16 uoe = uxh[tk * UXH + 8];
        const half8 un8 = *(const half8*)(uxh + row * UXH);
        const _Float16 une = uxh[row * UXH + 8];
        float e[KSc];
        float mx = -3.0e38f;
#pragma unroll
        for (int k = 0; k < 8; ++k) {
            e[k] = (float)uo8[k] - (float)un8[k] + ck[k];
            mx = fmaxf(mx, e[k]);
        }
        e[8] = (float)uoe - (float)une + ck[8];
        mx = fmaxf(mx, e[8]);
        float s = 0.f;
#pragma unroll
        for (int k = 0; k < KSc; ++k) { e[k] = __expf(e[k] - mx); s += e[k]; }
        const float r = pred ? (1.f / s) : 0.f;     // q=0 for padded neighbors
#pragma unroll
        for (int k = 0; k < KSc; ++k) qs[t][k][n] = e[k] * r;
    }
    // same-wave LDS write->read below: DS ops issue in order, no barrier needed

    // ---- fused y+pack+MFMA k-loop: y[9][8] never materialized ----
    floatx4 acc0 = {0.f, 0.f, 0.f, 0.f};
    floatx4 acc1 = {0.f, 0.f, 0.f, 0.f};
#pragma unroll
    for (int k = 0; k < KSc; ++k) {
        const float4 qa = *(const float4*)&qs[tA][k][0];
        const float4 qb = *(const float4*)&qs[tA][k][4];
        const float4 qc = *(const float4*)&qs[tA][k][8];
        float y8[8];
#pragma unroll
        for (int j = 0; j < 8; ++j) {               // n = 0..11 sequential
            float a = 0.f;
            a = fmaf(qa.x, xs[0][j], a);  a = fmaf(qa.y, xs[1][j], a);
            a = fmaf(qa.z, xs[2][j], a);  a = fmaf(qa.w, xs[3][j], a);
            a = fmaf(qb.x, xs[4][j], a);  a = fmaf(qb.y, xs[5][j], a);
            a = fmaf(qb.z, xs[6][j], a);  a = fmaf(qb.w, xs[7][j], a);
            a = fmaf(qc.x, xs[8][j], a);  a = fmaf(qc.y, xs[9][j], a);
            a = fmaf(qc.z, xs[10][j], a); a = fmaf(qc.w, xs[11][j], a);
            y8[j] = a;
        }
        half8 ah, al;
#pragma unroll
        for (int j = 0; j < 8; ++j) {
            const _Float16 hh = (_Float16)y8[j];
            ah[j] = hh;
            al[j] = (_Float16)(y8[j] - (float)hh);
        }
        const half8 bh0 = *(const half8*)(wf + ((k * 2 + 0) * 64 + l64) * 8);
        const half8 bh1 = *(const half8*)(wf + ((k * 2 + 1) * 64 + l64) * 8);
        const half8 bl0 = *(const half8*)(wf + WFE + ((k * 2 + 0) * 64 + l64) * 8);
        const half8 bl1 = *(const half8*)(wf + WFE + ((k * 2 + 1) * 64 + l64) * 8);
        acc0 = __builtin_amdgcn_mfma_f32_16x16x32_f16(ah, bh0, acc0, 0, 0, 0);
        acc0 = __builtin_amdgcn_mfma_f32_16x16x32_f16(al, bh0, acc0, 0, 0, 0);
        acc0 = __builtin_amdgcn_mfma_f32_16x16x32_f16(ah, bl0, acc0, 0, 0, 0);
        acc1 = __builtin_amdgcn_mfma_f32_16x16x32_f16(ah, bh1, acc1, 0, 0, 0);
        acc1 = __builtin_amdgcn_mfma_f32_16x16x32_f16(al, bh1, acc1, 0, 0, 0);
        acc1 = __builtin_amdgcn_mfma_f32_16x16x32_f16(ah, bl1, acc1, 0, 0, 0);
    }

    // ---- epilogue: D row = cb*4 + r (task), col = oo; inv via shfl; bias+relu ----
    const float b0 = bvec[oo], b1 = bvec[oo + 16];
#pragma unroll
    for (int r = 0; r < 4; ++r) {
        const int tl   = cb * 4 + r;
        const float nv = __shfl(inv_local, tl, 64);   // lane tl holds inv of task t0+tl
        const int tsk  = t0 + tl;
        out[tsk * OUTc + oo]      = fmaxf(fmaf(acc0[r], nv, b0), 0.f);
        out[tsk * OUTc + oo + 16] = fmaxf(fmaf(acc1[r], nv, b1), 0.f);
    }
}

extern "C" void kernel_launch(void* const* d_in, const int* in_sizes, int n_in,
                              void* d_out, int out_size, void* d_ws, size_t ws_size,
                              hipStream_t stream)
{
    const float* x    = (const float*)d_in[0];
    const float* W    = (const float*)d_in[1];
    const float* u    = (const float*)d_in[2];
    const float* cvec = (const float*)d_in[3];
    const float* bvec = (const float*)d_in[4];
    const int*   adj  = (const int*)d_in[5];
    float* out = (float*)d_out;

    _Float16* uxh = (_Float16*)d_ws;                              // 40000*16*2 = 1,280,000 B
    _Float16* xh  = (_Float16*)((char*)d_ws + 1280000);           // 40000*32*2 = 2,560,000 B
    _Float16* wf  = (_Float16*)((char*)d_ws + 1280000 + 2560000); // 2*9216*2   =    36,864 B

    prep_kernel<<<157 + 36, PBDIM, 0, stream>>>(x, u, W, uxh, xh, wf);
    fused_kernel<<<NITER, BDIM, 0, stream>>>(cvec, bvec, adj, uxh, xh, wf, out);
}